// Round 1
// baseline (615.760 us; speedup 1.0000x reference)
//
#include <hip/hip_runtime.h>
#include <math.h>

// Problem constants (from setup_inputs):
#define T_STEPS   4
#define NODE_NUM  10000
#define NUM_NODES 50000
#define E         256     // embedding dim
#define TWO_E     512
#define CC        128     // C
#define TWO_C     256
#define ROWS      16      // rows (output positions) per block in the MLP kernel

__device__ __forceinline__ float geluf(float v) {
    // exact gelu: 0.5*x*(1+erf(x/sqrt(2)))
    return 0.5f * v * (1.0f + erff(v * 0.70710678118654752440f));
}

__device__ __forceinline__ float f4c(const float4& v, int i) {
    switch (i & 3) {
        case 0: return v.x;
        case 1: return v.y;
        case 2: return v.z;
        default: return v.w;
    }
}

// Zero only the table rows that will be touched (duplicates re-zero: fine).
__global__ void zero_rows_kernel(float* __restrict__ table,
                                 const int* __restrict__ indices,
                                 int gr0, int t0) {
    int gr = gr0 + blockIdx.x;                 // global row id in [0, T*node_num)
    int trel = gr / NODE_NUM - t0;             // t within current ws slice
    int idx = indices[gr];
    table[((size_t)trel * NUM_NODES + idx) * E + threadIdx.x] = 0.0f;
}

// Scatter-add x rows into the per-t node table (duplicates must sum -> atomics).
__global__ void scatter_kernel(float* __restrict__ table,
                               const float* __restrict__ x,
                               const int* __restrict__ indices,
                               int gr0, int t0) {
    int gr = gr0 + blockIdx.x;
    int trel = gr / NODE_NUM - t0;
    int idx = indices[gr];
    atomicAdd(&table[((size_t)trel * NUM_NODES + idx) * E + threadIdx.x],
              x[(size_t)gr * E + threadIdx.x]);
}

// Fused: gather -> LN_d -> gelu(X@W1d+b1d) -> @W2d+b2d -> LN_u -> gelu(@W1u+b1u) -> @W2u+b2u
// One block = 16 output rows, 256 threads (4 waves). LDS buffers aliased: 48KB.
__global__ __launch_bounds__(256, 3)
void mlp_kernel(const float* __restrict__ table,
                const float* __restrict__ batched_x,
                const int* __restrict__ indices,
                const float* __restrict__ lnd_s, const float* __restrict__ lnd_b,
                const float* __restrict__ W1d, const float* __restrict__ b1d,
                const float* __restrict__ W2d, const float* __restrict__ b2d,
                const float* __restrict__ lnu_s, const float* __restrict__ lnu_b,
                const float* __restrict__ W1u, const float* __restrict__ b1u,
                const float* __restrict__ W2u, const float* __restrict__ b2u,
                float* __restrict__ out,
                int gr0, int t0) {
    // LDS layout (floats). Lifetimes:
    //   Xs  [16][256] @ 0      .. 4096   : dead after GEMM1
    //   H1s [16][512] @ 4096   .. 12288  : dead after GEMM2 inner loop
    //   H2s [16][128] @ 0      .. 2048   : written GEMM2 epilogue (Xs dead), dead after GEMM3
    //   G1s [16][256] @ 2048   .. 6144   : written GEMM3 epilogue, dead after GEMM4
    __shared__ float smem[12288];          // 48 KB
    __shared__ int idxs[ROWS];
    float (*Xs)[E]      = (float(*)[E])     (smem);
    float (*H1s)[TWO_E] = (float(*)[TWO_E]) (smem + 4096);
    float (*H2s)[CC]    = (float(*)[CC])    (smem);
    float (*G1s)[TWO_C] = (float(*)[TWO_C]) (smem + 2048);

    const int tid = threadIdx.x;
    const int grb = gr0 + blockIdx.x * ROWS;        // node_num % ROWS == 0 -> no t straddle
    const int trel = grb / NODE_NUM - t0;
    const float* tslice = table + (size_t)trel * NUM_NODES * E;

    if (tid < ROWS) idxs[tid] = indices[grb + tid];
    __syncthreads();

    // ---- Stage A: gather rows (table + batched_x) into LDS ----
    for (int r = 0; r < ROWS; ++r) {
        int idx = idxs[r];
        Xs[r][tid] = tslice[(size_t)idx * E + tid] + batched_x[(size_t)idx * E + tid];
    }
    __syncthreads();

    // ---- LN_d over E=256 per row: 16 lanes per row, strided cols ----
    {
        int row = tid >> 4, lane = tid & 15;
        float s = 0.f, sq = 0.f;
        #pragma unroll
        for (int k = 0; k < 16; ++k) {
            float v = Xs[row][k * 16 + lane];
            s += v; sq += v * v;
        }
        #pragma unroll
        for (int m = 8; m >= 1; m >>= 1) {
            s  += __shfl_xor(s,  m, 16);
            sq += __shfl_xor(sq, m, 16);
        }
        float mu = s * (1.0f / E);
        float var = sq * (1.0f / E) - mu * mu;
        float rs = rsqrtf(var + 1e-5f);
        #pragma unroll
        for (int k = 0; k < 16; ++k) {
            int c = k * 16 + lane;
            float v = Xs[row][c];
            Xs[row][c] = (v - mu) * rs * lnd_s[c] + lnd_b[c];
        }
    }
    __syncthreads();

    // ---- GEMM1: H1[16][512] = gelu(Xs[16][256] @ W1d + b1d) ----
    {
        int rt = tid >> 6, ct = tid & 63;           // wave = row-tile (LDS broadcast)
        int r0 = rt * 4, c0 = ct * 8;
        float acc[4][8];
        #pragma unroll
        for (int r = 0; r < 4; ++r)
            #pragma unroll
            for (int c = 0; c < 8; ++c) acc[r][c] = 0.f;
        for (int i = 0; i < E; i += 4) {
            float4 xv[4];
            #pragma unroll
            for (int r = 0; r < 4; ++r)
                xv[r] = *reinterpret_cast<const float4*>(&Xs[r0 + r][i]);
            #pragma unroll
            for (int ii = 0; ii < 4; ++ii) {
                float4 wA = *reinterpret_cast<const float4*>(&W1d[(size_t)(i + ii) * TWO_E + c0]);
                float4 wB = *reinterpret_cast<const float4*>(&W1d[(size_t)(i + ii) * TWO_E + c0 + 4]);
                #pragma unroll
                for (int r = 0; r < 4; ++r) {
                    float xs = f4c(xv[r], ii);
                    acc[r][0] += xs * wA.x; acc[r][1] += xs * wA.y;
                    acc[r][2] += xs * wA.z; acc[r][3] += xs * wA.w;
                    acc[r][4] += xs * wB.x; acc[r][5] += xs * wB.y;
                    acc[r][6] += xs * wB.z; acc[r][7] += xs * wB.w;
                }
            }
        }
        float4 b1 = *reinterpret_cast<const float4*>(&b1d[c0]);
        float4 b2 = *reinterpret_cast<const float4*>(&b1d[c0 + 4]);
        #pragma unroll
        for (int r = 0; r < 4; ++r) {
            float4 o1, o2;
            o1.x = geluf(acc[r][0] + b1.x); o1.y = geluf(acc[r][1] + b1.y);
            o1.z = geluf(acc[r][2] + b1.z); o1.w = geluf(acc[r][3] + b1.w);
            o2.x = geluf(acc[r][4] + b2.x); o2.y = geluf(acc[r][5] + b2.y);
            o2.z = geluf(acc[r][6] + b2.z); o2.w = geluf(acc[r][7] + b2.w);
            *reinterpret_cast<float4*>(&H1s[r0 + r][c0])     = o1;
            *reinterpret_cast<float4*>(&H1s[r0 + r][c0 + 4]) = o2;
        }
    }
    __syncthreads();

    // ---- GEMM2: H2[16][128] = H1[16][512] @ W2d + b2d  (no gelu) ----
    {
        int rt = tid >> 6, ct = tid & 63;
        int r0 = rt * 4, c0 = ct * 2;
        float acc[4][2];
        #pragma unroll
        for (int r = 0; r < 4; ++r) { acc[r][0] = 0.f; acc[r][1] = 0.f; }
        for (int i = 0; i < TWO_E; i += 4) {
            float4 xv[4];
            #pragma unroll
            for (int r = 0; r < 4; ++r)
                xv[r] = *reinterpret_cast<const float4*>(&H1s[r0 + r][i]);
            #pragma unroll
            for (int ii = 0; ii < 4; ++ii) {
                float2 w = *reinterpret_cast<const float2*>(&W2d[(size_t)(i + ii) * CC + c0]);
                #pragma unroll
                for (int r = 0; r < 4; ++r) {
                    float xs = f4c(xv[r], ii);
                    acc[r][0] += xs * w.x; acc[r][1] += xs * w.y;
                }
            }
        }
        // H2s aliases Xs (dead). Barrier above GEMM2 already passed; write after all H1 reads
        // of THIS thread; other threads write disjoint H2 cells, H2 region != H1 region.
        float bx0 = b2d[c0], bx1 = b2d[c0 + 1];
        #pragma unroll
        for (int r = 0; r < 4; ++r) {
            H2s[r0 + r][c0]     = acc[r][0] + bx0;
            H2s[r0 + r][c0 + 1] = acc[r][1] + bx1;
        }
    }
    __syncthreads();

    // ---- LN_u over C=128 per row ----
    {
        int row = tid >> 4, lane = tid & 15;
        float s = 0.f, sq = 0.f;
        #pragma unroll
        for (int k = 0; k < 8; ++k) {
            float v = H2s[row][k * 16 + lane];
            s += v; sq += v * v;
        }
        #pragma unroll
        for (int m = 8; m >= 1; m >>= 1) {
            s  += __shfl_xor(s,  m, 16);
            sq += __shfl_xor(sq, m, 16);
        }
        float mu = s * (1.0f / CC);
        float var = sq * (1.0f / CC) - mu * mu;
        float rs = rsqrtf(var + 1e-5f);
        #pragma unroll
        for (int k = 0; k < 8; ++k) {
            int c = k * 16 + lane;
            float v = H2s[row][c];
            H2s[row][c] = (v - mu) * rs * lnu_s[c] + lnu_b[c];
        }
    }
    __syncthreads();

    // ---- GEMM3: G1[16][256] = gelu(H2[16][128] @ W1u + b1u) ----
    {
        int rt = tid >> 6, ct = tid & 63;
        int r0 = rt * 4, c0 = ct * 4;
        float acc[4][4];
        #pragma unroll
        for (int r = 0; r < 4; ++r)
            #pragma unroll
            for (int c = 0; c < 4; ++c) acc[r][c] = 0.f;
        for (int i = 0; i < CC; i += 4) {
            float4 xv[4];
            #pragma unroll
            for (int r = 0; r < 4; ++r)
                xv[r] = *reinterpret_cast<const float4*>(&H2s[r0 + r][i]);
            #pragma unroll
            for (int ii = 0; ii < 4; ++ii) {
                float4 w = *reinterpret_cast<const float4*>(&W1u[(size_t)(i + ii) * TWO_C + c0]);
                #pragma unroll
                for (int r = 0; r < 4; ++r) {
                    float xs = f4c(xv[r], ii);
                    acc[r][0] += xs * w.x; acc[r][1] += xs * w.y;
                    acc[r][2] += xs * w.z; acc[r][3] += xs * w.w;
                }
            }
        }
        float4 b = *reinterpret_cast<const float4*>(&b1u[c0]);
        #pragma unroll
        for (int r = 0; r < 4; ++r) {
            float4 o;
            o.x = geluf(acc[r][0] + b.x); o.y = geluf(acc[r][1] + b.y);
            o.z = geluf(acc[r][2] + b.z); o.w = geluf(acc[r][3] + b.w);
            *reinterpret_cast<float4*>(&G1s[r0 + r][c0]) = o;
        }
    }
    __syncthreads();

    // ---- GEMM4: out[16][256] = G1[16][256] @ W2u + b2u ----
    {
        int rt = tid >> 6, ct = tid & 63;
        int r0 = rt * 4, c0 = ct * 4;
        float acc[4][4];
        #pragma unroll
        for (int r = 0; r < 4; ++r)
            #pragma unroll
            for (int c = 0; c < 4; ++c) acc[r][c] = 0.f;
        for (int i = 0; i < TWO_C; i += 4) {
            float4 xv[4];
            #pragma unroll
            for (int r = 0; r < 4; ++r)
                xv[r] = *reinterpret_cast<const float4*>(&G1s[r0 + r][i]);
            #pragma unroll
            for (int ii = 0; ii < 4; ++ii) {
                float4 w = *reinterpret_cast<const float4*>(&W2u[(size_t)(i + ii) * E + c0]);
                #pragma unroll
                for (int r = 0; r < 4; ++r) {
                    float xs = f4c(xv[r], ii);
                    acc[r][0] += xs * w.x; acc[r][1] += xs * w.y;
                    acc[r][2] += xs * w.z; acc[r][3] += xs * w.w;
                }
            }
        }
        float4 b = *reinterpret_cast<const float4*>(&b2u[c0]);
        #pragma unroll
        for (int r = 0; r < 4; ++r) {
            float4 o;
            o.x = acc[r][0] + b.x; o.y = acc[r][1] + b.y;
            o.z = acc[r][2] + b.z; o.w = acc[r][3] + b.w;
            *reinterpret_cast<float4*>(&out[(size_t)(grb + r0 + r) * E + c0]) = o;
        }
    }
}

extern "C" void kernel_launch(void* const* d_in, const int* in_sizes, int n_in,
                              void* d_out, int out_size, void* d_ws, size_t ws_size,
                              hipStream_t stream) {
    const float* x     = (const float*)d_in[0];
    const float* bx    = (const float*)d_in[1];
    const int*   idxp  = (const int*)  d_in[2];
    const float* lnd_s = (const float*)d_in[3];
    const float* lnd_b = (const float*)d_in[4];
    const float* W1d   = (const float*)d_in[5];
    const float* b1d   = (const float*)d_in[6];
    const float* W2d   = (const float*)d_in[7];
    const float* b2d   = (const float*)d_in[8];
    const float* lnu_s = (const float*)d_in[9];
    const float* lnu_b = (const float*)d_in[10];
    const float* W1u   = (const float*)d_in[11];
    const float* b1u   = (const float*)d_in[12];
    const float* W2u   = (const float*)d_in[13];
    const float* b2u   = (const float*)d_in[14];
    float* out   = (float*)d_out;
    float* table = (float*)d_ws;

    // t-slices of the scatter table that fit in ws (51.2 MB per t).
    const size_t slice_bytes = (size_t)NUM_NODES * E * sizeof(float);
    int tb = (int)(ws_size / slice_bytes);
    if (tb < 1) tb = 1;           // assume ws >= 51.2MB; loop keeps it correct if == 1..3
    if (tb > T_STEPS) tb = T_STEPS;

    for (int t0 = 0; t0 < T_STEPS; t0 += tb) {
        int tcur = T_STEPS - t0 < tb ? T_STEPS - t0 : tb;
        int nrows = tcur * NODE_NUM;
        int gr0 = t0 * NODE_NUM;
        zero_rows_kernel<<<nrows, E, 0, stream>>>(table, idxp, gr0, t0);
        scatter_kernel  <<<nrows, E, 0, stream>>>(table, x, idxp, gr0, t0);
        mlp_kernel<<<nrows / ROWS, 256, 0, stream>>>(
            table, bx, idxp, lnd_s, lnd_b, W1d, b1d, W2d, b2d,
            lnu_s, lnu_b, W1u, b1u, W2u, b2u, out, gr0, t0);
    }
}

// Round 4
// 298.516 us; speedup vs baseline: 2.0627x; 2.0627x over previous
//
#include <hip/hip_runtime.h>
#include <math.h>

// Problem constants (from setup_inputs):
#define T_STEPS   4
#define NODE_NUM  10000
#define NUM_NODES 50000
#define E         256     // embedding dim
#define TWO_E     512
#define CC        128     // C
#define TWO_C     256
#define ROWS      32      // rows per block in the MLP kernel

typedef short bf16x8 __attribute__((ext_vector_type(8)));   // 8 bf16 = 4 VGPRs
typedef float f32x4  __attribute__((ext_vector_type(4)));   // MFMA accumulator

#define MFMA16(a, b, c) __builtin_amdgcn_mfma_f32_16x16x32_bf16((a), (b), (c), 0, 0, 0)

// bf16 weights, transposed [N][K], module-scope device global: d_ws is left
// entirely for the scatter table (the R2 ws-overrun fault is impossible here).
// layout (elements): w1t @0 (512x256), w2t @131072 (128x512),
//                    w1ut @196608 (256x128), w2ut @229376 (256x256)
static __device__ unsigned short g_wt[294912];

__device__ __forceinline__ float geluf(float v) {
    return 0.5f * v * (1.0f + erff(v * 0.70710678118654752440f));
}

// fp32 -> bf16 round-to-nearest-even (finite inputs only)
__device__ __forceinline__ unsigned short f2bf(float f) {
    unsigned int u = __builtin_bit_cast(unsigned int, f);
    u += 0x7fffu + ((u >> 16) & 1u);
    return (unsigned short)(u >> 16);
}

// ---------------- weight prep: fp32 [K][N] -> bf16 [N][K] ----------------
__global__ void prep_weights(const float* __restrict__ W1d, const float* __restrict__ W2d,
                             const float* __restrict__ W1u, const float* __restrict__ W2u) {
    int i = blockIdx.x * 256 + threadIdx.x;       // 0 .. 131071
    if (i < 131072) {  // w1t: [512][256] <- W1d [256][512]
        int n = i >> 8, k = i & 255;
        g_wt[i] = f2bf(W1d[(size_t)k * TWO_E + n]);
    }
    if (i < 65536) {   // w2t: [128][512] <- W2d [512][128]
        int n = i >> 9, k = i & 511;
        g_wt[131072 + i] = f2bf(W2d[(size_t)k * CC + n]);
    }
    if (i < 32768) {   // w1ut: [256][128] <- W1u [128][256]
        int n = i >> 7, k = i & 127;
        g_wt[196608 + i] = f2bf(W1u[(size_t)k * TWO_C + n]);
    }
    if (i < 65536) {   // w2ut: [256][256] <- W2u [256][256]
        int n = i >> 8, k = i & 255;
        g_wt[229376 + i] = f2bf(W2u[(size_t)k * E + n]);
    }
}

// ---------------- zero active table rows (float4, 4 rows/block) ----------------
__global__ void zero_rows_kernel(float* __restrict__ table,
                                 const int* __restrict__ indices,
                                 int gr0, int t0) {
    int gr = gr0 + blockIdx.x * 4 + (threadIdx.x >> 6);
    int trel = gr / NODE_NUM - t0;
    int idx = indices[gr];
    int c = (threadIdx.x & 63) * 4;
    float4 z = make_float4(0.f, 0.f, 0.f, 0.f);
    *reinterpret_cast<float4*>(&table[((size_t)trel * NUM_NODES + idx) * E + c]) = z;
}

// ---------------- scatter-add (duplicates must sum -> atomics) ----------------
__global__ void scatter_kernel(float* __restrict__ table,
                               const float* __restrict__ x,
                               const int* __restrict__ indices,
                               int gr0, int t0) {
    int gr = gr0 + blockIdx.x;
    int trel = gr / NODE_NUM - t0;
    int idx = indices[gr];
    atomicAdd(&table[((size_t)trel * NUM_NODES + idx) * E + threadIdx.x],
              x[(size_t)gr * E + threadIdx.x]);
}

// ---------------- fused gather -> LN_d -> MLP_d -> LN_u -> MLP_u ----------------
// 32 rows/block, 256 threads (4 waves). bf16 MFMA 16x16x32, fp32 accumulate.
// LDS aliasing (bytes):
//   region A [0, 33280):     Xf fp32 [32][260]  ->  H1 bf16 [32][520]
//                            -> H2b bf16 [32][136] @0 + G1 bf16 [32][264] @8704
//   region B [33280, 50176): Xs bf16 [32][264]  ->  H2f fp32 [32][132]
__global__ __launch_bounds__(256, 3)
void mlp_kernel(const float* __restrict__ table,
                const float* __restrict__ batched_x,
                const int* __restrict__ indices,
                const float* __restrict__ lnd_s, const float* __restrict__ lnd_b,
                const float* __restrict__ b1d, const float* __restrict__ b2d,
                const float* __restrict__ lnu_s, const float* __restrict__ lnu_b,
                const float* __restrict__ b1u, const float* __restrict__ b2u,
                float* __restrict__ out,
                int gr0, int t0, int grLim) {
    __shared__ __align__(16) unsigned char smem[50176];
    __shared__ size_t rbase[ROWS];
    __shared__ int    ridx[ROWS];

    float*          Xf  = (float*)smem;                         // [32][260]
    unsigned short* Xs  = (unsigned short*)(smem + 33280);      // [32][264]
    unsigned short* H1  = (unsigned short*)smem;                // [32][520]
    float*          H2f = (float*)(smem + 33280);               // [32][132]
    unsigned short* H2b = (unsigned short*)smem;                // [32][136]
    unsigned short* G1  = (unsigned short*)(smem + 8704);       // [32][264]

    const unsigned short* w1t  = g_wt;
    const unsigned short* w2t  = g_wt + 131072;
    const unsigned short* w1ut = g_wt + 196608;
    const unsigned short* w2ut = g_wt + 229376;

    const int tid = threadIdx.x;
    const int w = tid >> 6, lane = tid & 63;
    const int l16 = lane & 15, quad = lane >> 4;
    const int grb = gr0 + blockIdx.x * ROWS;

    if (tid < ROWS) {
        int gr = grb + tid;
        if (gr >= grLim) gr = grLim - 1;     // clamped dup row; out-store guarded later
        int trel = gr / NODE_NUM - t0;
        int idx = indices[gr];
        rbase[tid] = ((size_t)trel * NUM_NODES + idx) * E;
        ridx[tid]  = idx;
    }
    __syncthreads();

    // ---- gather: Xf = table_row + batched_x_row (fp32) ----
    #pragma unroll
    for (int it = 0; it < 8; ++it) {
        int v = it * 256 + tid;
        int r = v >> 6;
        int c = (v & 63) * 4;
        float4 tv = *reinterpret_cast<const float4*>(&table[rbase[r] + c]);
        float4 bv = *reinterpret_cast<const float4*>(&batched_x[(size_t)ridx[r] * E + c]);
        float4 s; s.x = tv.x + bv.x; s.y = tv.y + bv.y; s.z = tv.z + bv.z; s.w = tv.w + bv.w;
        *reinterpret_cast<float4*>(&Xf[r * 260 + c]) = s;
    }
    __syncthreads();

    // ---- LN_d (E=256): 8 lanes/row, then cvt bf16 -> Xs ----
    {
        int row = tid >> 3, l8 = tid & 7;
        float s = 0.f, sq = 0.f;
        #pragma unroll
        for (int k = 0; k < 32; ++k) {
            float v = Xf[row * 260 + k * 8 + l8];
            s += v; sq += v * v;
        }
        s  += __shfl_xor(s, 1);  s  += __shfl_xor(s, 2);  s  += __shfl_xor(s, 4);
        sq += __shfl_xor(sq, 1); sq += __shfl_xor(sq, 2); sq += __shfl_xor(sq, 4);
        float mu = s * (1.0f / E);
        float var = sq * (1.0f / E) - mu * mu;
        float rs = rsqrtf(var + 1e-5f);
        #pragma unroll
        for (int k = 0; k < 32; ++k) {
            int c = k * 8 + l8;
            float v = (Xf[row * 260 + c] - mu) * rs * lnd_s[c] + lnd_b[c];
            Xs[row * 264 + c] = f2bf(v);
        }
    }
    __syncthreads();

    // ---- GEMM1: H1[32][512] = gelu(Xs @ W1d + b1d), K=256 ----
    {
        bf16x8 af[2][8];
        #pragma unroll
        for (int mt = 0; mt < 2; ++mt) {
            const unsigned short* base = Xs + (l16 + 16 * mt) * 264 + quad * 8;
            #pragma unroll
            for (int ks = 0; ks < 8; ++ks)
                af[mt][ks] = *reinterpret_cast<const bf16x8*>(base + ks * 32);
        }
        #pragma unroll
        for (int nt_ = 0; nt_ < 8; ++nt_) {
            int n = (w * 8 + nt_) * 16 + l16;
            const unsigned short* bp = w1t + (size_t)n * 256 + quad * 8;
            f32x4 a0 = {0.f, 0.f, 0.f, 0.f}, a1 = {0.f, 0.f, 0.f, 0.f};
            #pragma unroll
            for (int ks = 0; ks < 8; ++ks) {
                bf16x8 b = *reinterpret_cast<const bf16x8*>(bp + ks * 32);
                a0 = MFMA16(af[0][ks], b, a0);
                a1 = MFMA16(af[1][ks], b, a1);
            }
            float bias = b1d[n];
            #pragma unroll
            for (int reg = 0; reg < 4; ++reg) {
                int r = quad * 4 + reg;
                H1[r * 520 + n]        = f2bf(geluf(a0[reg] + bias));
                H1[(r + 16) * 520 + n] = f2bf(geluf(a1[reg] + bias));
            }
        }
    }
    __syncthreads();

    // ---- GEMM2: H2f[32][128] = H1 @ W2d + b2d (fp32 out), K=512 ----
    {
        f32x4 acc2[2][2];
        #pragma unroll
        for (int i = 0; i < 2; ++i)
            #pragma unroll
            for (int j = 0; j < 2; ++j) acc2[i][j] = (f32x4){0.f, 0.f, 0.f, 0.f};
        #pragma unroll
        for (int kh = 0; kh < 2; ++kh) {
            bf16x8 af2[2][8];
            #pragma unroll
            for (int mt = 0; mt < 2; ++mt) {
                const unsigned short* base = H1 + (l16 + 16 * mt) * 520 + kh * 256 + quad * 8;
                #pragma unroll
                for (int ks = 0; ks < 8; ++ks)
                    af2[mt][ks] = *reinterpret_cast<const bf16x8*>(base + ks * 32);
            }
            #pragma unroll
            for (int nt2 = 0; nt2 < 2; ++nt2) {
                int n = (w * 2 + nt2) * 16 + l16;
                const unsigned short* bp = w2t + (size_t)n * 512 + kh * 256 + quad * 8;
                #pragma unroll
                for (int ks = 0; ks < 8; ++ks) {
                    bf16x8 b = *reinterpret_cast<const bf16x8*>(bp + ks * 32);
                    acc2[nt2][0] = MFMA16(af2[0][ks], b, acc2[nt2][0]);
                    acc2[nt2][1] = MFMA16(af2[1][ks], b, acc2[nt2][1]);
                }
            }
        }
        #pragma unroll
        for (int nt2 = 0; nt2 < 2; ++nt2) {
            int n = (w * 2 + nt2) * 16 + l16;
            float bias = b2d[n];
            #pragma unroll
            for (int mt = 0; mt < 2; ++mt)
                #pragma unroll
                for (int reg = 0; reg < 4; ++reg) {
                    int r = mt * 16 + quad * 4 + reg;
                    H2f[r * 132 + n] = acc2[nt2][mt][reg] + bias;
                }
        }
    }
    __syncthreads();

    // ---- LN_u (C=128): 8 lanes/row, cvt bf16 -> H2b ----
    {
        int row = tid >> 3, l8 = tid & 7;
        float s = 0.f, sq = 0.f;
        #pragma unroll
        for (int k = 0; k < 16; ++k) {
            float v = H2f[row * 132 + k * 8 + l8];
            s += v; sq += v * v;
        }
        s  += __shfl_xor(s, 1);  s  += __shfl_xor(s, 2);  s  += __shfl_xor(s, 4);
        sq += __shfl_xor(sq, 1); sq += __shfl_xor(sq, 2); sq += __shfl_xor(sq, 4);
        float mu = s * (1.0f / CC);
        float var = sq * (1.0f / CC) - mu * mu;
        float rs = rsqrtf(var + 1e-5f);
        #pragma unroll
        for (int k = 0; k < 16; ++k) {
            int c = k * 8 + l8;
            float v = (H2f[row * 132 + c] - mu) * rs * lnu_s[c] + lnu_b[c];
            H2b[row * 136 + c] = f2bf(v);
        }
    }
    __syncthreads();

    // ---- GEMM3: G1[32][256] = gelu(H2b @ W1u + b1u), K=128 ----
    {
        bf16x8 af3[2][4];
        #pragma unroll
        for (int mt = 0; mt < 2; ++mt) {
            const unsigned short* base = H2b + (l16 + 16 * mt) * 136 + quad * 8;
            #pragma unroll
            for (int ks = 0; ks < 4; ++ks)
                af3[mt][ks] = *reinterpret_cast<const bf16x8*>(base + ks * 32);
        }
        #pragma unroll
        for (int nt_ = 0; nt_ < 4; ++nt_) {
            int n = (w * 4 + nt_) * 16 + l16;
            const unsigned short* bp = w1ut + (size_t)n * 128 + quad * 8;
            f32x4 a0 = {0.f, 0.f, 0.f, 0.f}, a1 = {0.f, 0.f, 0.f, 0.f};
            #pragma unroll
            for (int ks = 0; ks < 4; ++ks) {
                bf16x8 b = *reinterpret_cast<const bf16x8*>(bp + ks * 32);
                a0 = MFMA16(af3[0][ks], b, a0);
                a1 = MFMA16(af3[1][ks], b, a1);
            }
            float bias = b1u[n];
            #pragma unroll
            for (int reg = 0; reg < 4; ++reg) {
                int r = quad * 4 + reg;
                G1[r * 264 + n]        = f2bf(geluf(a0[reg] + bias));
                G1[(r + 16) * 264 + n] = f2bf(geluf(a1[reg] + bias));
            }
        }
    }
    __syncthreads();

    // ---- GEMM4: out[32][256] = G1 @ W2u + b2u (fp32 global), K=256 ----
    {
        bf16x8 af4[2][8];
        #pragma unroll
        for (int mt = 0; mt < 2; ++mt) {
            const unsigned short* base = G1 + (l16 + 16 * mt) * 264 + quad * 8;
            #pragma unroll
            for (int ks = 0; ks < 8; ++ks)
                af4[mt][ks] = *reinterpret_cast<const bf16x8*>(base + ks * 32);
        }
        #pragma unroll
        for (int nt_ = 0; nt_ < 4; ++nt_) {
            int n = (w * 4 + nt_) * 16 + l16;
            const unsigned short* bp = w2ut + (size_t)n * 256 + quad * 8;
            f32x4 a0 = {0.f, 0.f, 0.f, 0.f}, a1 = {0.f, 0.f, 0.f, 0.f};
            #pragma unroll
            for (int ks = 0; ks < 8; ++ks) {
                bf16x8 b = *reinterpret_cast<const bf16x8*>(bp + ks * 32);
                a0 = MFMA16(af4[0][ks], b, a0);
                a1 = MFMA16(af4[1][ks], b, a1);
            }
            float bias = b2u[n];
            #pragma unroll
            for (int reg = 0; reg < 4; ++reg) {
                int r = quad * 4 + reg;
                int g0 = grb + r, g1 = grb + r + 16;
                if (g0 < grLim) out[(size_t)g0 * E + n] = a0[reg] + bias;
                if (g1 < grLim) out[(size_t)g1 * E + n] = a1[reg] + bias;
            }
        }
    }
}

extern "C" void kernel_launch(void* const* d_in, const int* in_sizes, int n_in,
                              void* d_out, int out_size, void* d_ws, size_t ws_size,
                              hipStream_t stream) {
    const float* x     = (const float*)d_in[0];
    const float* bx    = (const float*)d_in[1];
    const int*   idxp  = (const int*)  d_in[2];
    const float* lnd_s = (const float*)d_in[3];
    const float* lnd_b = (const float*)d_in[4];
    const float* W1d   = (const float*)d_in[5];
    const float* b1d   = (const float*)d_in[6];
    const float* W2d   = (const float*)d_in[7];
    const float* b2d   = (const float*)d_in[8];
    const float* lnu_s = (const float*)d_in[9];
    const float* lnu_b = (const float*)d_in[10];
    const float* W1u   = (const float*)d_in[11];
    const float* b1u   = (const float*)d_in[12];
    const float* W2u   = (const float*)d_in[13];
    const float* b2u   = (const float*)d_in[14];
    float* out = (float*)d_out;
    float* table = (float*)d_ws;     // full ws for table slices (weights in g_wt)

    const size_t slice_bytes = (size_t)NUM_NODES * E * sizeof(float);
    int tb = (int)(ws_size / slice_bytes);
    if (tb < 1) tb = 1;              // R1 passed with this assumption: ws >= 1 slice
    if (tb > T_STEPS) tb = T_STEPS;

    prep_weights<<<512, 256, 0, stream>>>(W1d, W2d, W1u, W2u);

    for (int t0 = 0; t0 < T_STEPS; t0 += tb) {
        int tcur = T_STEPS - t0 < tb ? T_STEPS - t0 : tb;
        int nrows = tcur * NODE_NUM;
        int gr0 = t0 * NODE_NUM;
        int grLim = gr0 + nrows;
        zero_rows_kernel<<<nrows / 4, 256, 0, stream>>>(table, idxp, gr0, t0);
        scatter_kernel  <<<nrows, E, 0, stream>>>(table, x, idxp, gr0, t0);
        mlp_kernel<<<(nrows + ROWS - 1) / ROWS, 256, 0, stream>>>(
            table, bx, idxp, lnd_s, lnd_b, b1d, b2d,
            lnu_s, lnu_b, b1u, b2u, out, gr0, t0, grLim);
    }
}